// Round 7
// baseline (340.969 us; speedup 1.0000x reference)
//
#include <hip/hip_runtime.h>
#include <hip/hip_fp16.h>

#define N_NODES 100000
#define D_FEAT  64
#define N_EDGES 1600000
#define NPB     128                         // nodes per bucket (dst >> 7)
#define NBUCK   ((N_NODES + NPB - 1) / NPB) // 782
#define NPART   512                         // partition chunks
#define CHUNK   (N_EDGES / NPART)           // 3125 (exact)

// ---------- phase 0: X -> fp16 copy ----------
__global__ void cvt_fp16(const float* __restrict__ X, __half* __restrict__ Xh) {
    int i = blockIdx.x * blockDim.x + threadIdx.x;
    const int n4 = N_NODES * D_FEAT / 4;
    if (i >= n4) return;
    float4 v = ((const float4*)X)[i];
    __half2 a = __floats2half2_rn(v.x, v.y);
    __half2 b = __floats2half2_rn(v.z, v.w);
    ((__half2*)Xh)[2 * i]     = a;
    ((__half2*)Xh)[2 * i + 1] = b;
}

// ---------- phase 1: per-chunk histogram over buckets ----------
__global__ void count_chunks(const int* __restrict__ dst, int* __restrict__ gcount) {
    __shared__ int h[NBUCK];
    for (int i = threadIdx.x; i < NBUCK; i += blockDim.x) h[i] = 0;
    __syncthreads();
    const int beg = blockIdx.x * CHUNK, end = beg + CHUNK;
    for (int i = beg + threadIdx.x; i < end; i += blockDim.x)
        atomicAdd(&h[dst[i] >> 7], 1);
    __syncthreads();
    for (int i = threadIdx.x; i < NBUCK; i += blockDim.x)
        gcount[blockIdx.x * NBUCK + i] = h[i];
}

// ---------- phase 2a: per-bucket scan over the 512 chunks ----------
__global__ __launch_bounds__(NPART) void scan_chunks(const int* __restrict__ gcount,
                                                     int* __restrict__ goff,
                                                     int* __restrict__ tot) {
    __shared__ int tmp[NPART];
    const int t = threadIdx.x;      // chunk id
    const int b = blockIdx.x;       // bucket id
    int v = gcount[t * NBUCK + b];
    tmp[t] = v;
    __syncthreads();
    for (int off = 1; off < NPART; off <<= 1) {
        int u = (t >= off) ? tmp[t - off] : 0;
        __syncthreads();
        tmp[t] += u;
        __syncthreads();
    }
    goff[t * NBUCK + b] = tmp[t] - v;
    if (t == NPART - 1) tot[b] = tmp[t];
}

// ---------- phase 2b: scan 782 bucket totals -> bptr ----------
__global__ void scan_tot(const int* __restrict__ tot, int* __restrict__ bptr,
                         int* __restrict__ row_ptr) {
    __shared__ int tmp[1024];
    const int t = threadIdx.x;
    int v = (t < NBUCK) ? tot[t] : 0;
    tmp[t] = v;
    __syncthreads();
    for (int off = 1; off < 1024; off <<= 1) {
        int u = (t >= off) ? tmp[t - off] : 0;
        __syncthreads();
        tmp[t] += u;
        __syncthreads();
    }
    if (t < NBUCK) bptr[t] = tmp[t] - v;
    if (t == 0) {
        bptr[NBUCK] = N_EDGES;
        row_ptr[N_NODES] = N_EDGES;
    }
}

// ---------- phase 3: deterministic partition via LDS cursors ----------
// packed word = src | (dst & 127) << 17   (src < 2^17)
__global__ void partition_chunks(const int* __restrict__ src, const int* __restrict__ dst,
                                 const float* __restrict__ ew, const int* __restrict__ goff,
                                 const int* __restrict__ bptr, int2* __restrict__ bedges) {
    __shared__ int cur[NBUCK];
    for (int i = threadIdx.x; i < NBUCK; i += blockDim.x)
        cur[i] = goff[blockIdx.x * NBUCK + i] + bptr[i];
    __syncthreads();
    const int beg = blockIdx.x * CHUNK, end = beg + CHUNK;
    for (int i = beg + threadIdx.x; i < end; i += blockDim.x) {
        int d = dst[i];
        int b = d >> 7;
        int p = atomicAdd(&cur[b], 1);
        int2 e;
        e.x = src[i] | ((d & (NPB - 1)) << 17);
        e.y = __float_as_int(ew[i]);
        bedges[p] = e;
    }
}

// ---------- phase 4: per-bucket LDS counting sort -> dst-sorted edges + row_ptr ----------
__global__ void sort_bucket(const int2* __restrict__ bedges, const int* __restrict__ bptr,
                            int2* __restrict__ sedges, int* __restrict__ row_ptr) {
    __shared__ int cnt[NPB];
    __shared__ int sc[NPB];
    __shared__ int cur[NPB];
    const int b = blockIdx.x;
    const int t = threadIdx.x;
    const int beg = bptr[b];
    const int end = bptr[b + 1];

    if (t < NPB) cnt[t] = 0;
    __syncthreads();
    for (int i = beg + t; i < end; i += blockDim.x)
        atomicAdd(&cnt[bedges[i].x >> 17], 1);
    __syncthreads();

    if (t < NPB) sc[t] = cnt[t];
    __syncthreads();
    for (int off = 1; off < NPB; off <<= 1) {
        int v = (t >= off && t < NPB) ? sc[t - off] : 0;
        __syncthreads();
        if (t < NPB) sc[t] += v;
        __syncthreads();
    }
    if (t < NPB) {
        int ex = sc[t] - cnt[t];
        cur[t] = ex;
        int node = b * NPB + t;
        if (node < N_NODES) row_ptr[node] = beg + ex;
    }
    __syncthreads();

    for (int i = beg + t; i < end; i += blockDim.x) {
        int2 e = bedges[i];
        int dl = e.x >> 17;
        int p = atomicAdd(&cur[dl], 1);
        int2 o;
        o.x = e.x & 0x1FFFF;
        o.y = e.y;
        sedges[beg + p] = o;
    }
}

// ---------- phase 5: pull SpMM — scalar edges, fp16 gathers, 16-wide batches ----------
// One 64-lane wave per destination node; lane = feature.
// MODE 0/1: hout = half(a) | MODE 2: out = (X + h1 + h2 + a) * 0.25
template <int MODE>
__global__ __launch_bounds__(256) void spmm_pull(const __half* __restrict__ hprev,
                                                 const int* __restrict__ row_ptr,
                                                 const int2* __restrict__ edges,
                                                 __half* __restrict__ hout,
                                                 float* __restrict__ out,
                                                 const float* __restrict__ X,
                                                 const __half* __restrict__ h1,
                                                 const __half* __restrict__ h2) {
    int node = blockIdx.x * 4 + (threadIdx.x >> 6);
    int lane = threadIdx.x & 63;
    if (node >= N_NODES) return;

    int beg = __builtin_amdgcn_readfirstlane(row_ptr[node]);
    int end = __builtin_amdgcn_readfirstlane(row_ptr[node + 1]);

    float a = 0.0f;
    for (int j = beg; j < end; j += 16) {
        float t[16], w[16];
        #pragma unroll
        for (int k = 0; k < 16; ++k) {
            int jk = j + k;
            int idx = (jk < end) ? jk : beg;      // clamp (scalar, branch-free)
            int2 e = edges[idx];                  // s_load: uniform addr
            w[k] = (jk < end) ? __int_as_float(e.y) : 0.0f;
            t[k] = __half2float(hprev[((size_t)e.x << 6) | lane]);  // 128B/wave
        }
        #pragma unroll
        for (int k = 0; k < 16; ++k)
            a += t[k] * w[k];
    }

    size_t idx = ((size_t)node << 6) | lane;
    if (MODE == 2)
        out[idx] = (X[idx] + __half2float(h1[idx]) + __half2float(h2[idx]) + a) * 0.25f;
    else
        hout[idx] = __float2half(a);
}

extern "C" void kernel_launch(void* const* d_in, const int* in_sizes, int n_in,
                              void* d_out, int out_size, void* d_ws, size_t ws_size,
                              hipStream_t stream) {
    const float* X   = (const float*)d_in[0];
    const int*   src = (const int*)  d_in[1];
    const int*   dst = (const int*)  d_in[2];
    const float* ew  = (const float*)d_in[3];
    float* out = (float*)d_out;

    const size_t feat = (size_t)N_NODES * D_FEAT;

    char* p = (char*)d_ws;
    __half* hA     = (__half*)p; p += feat * sizeof(__half);       // 12.8 MB
    __half* hB     = (__half*)p; p += feat * sizeof(__half);       // 12.8 MB
    __half* Xh     = (__half*)p; p += feat * sizeof(__half);       // 12.8 MB
    int2*  bedges  = (int2*)p;   p += (size_t)N_EDGES * 8;         // 12.8 MB
    int2*  sedges  = (int2*)p;   p += (size_t)N_EDGES * 8;         // 12.8 MB
    int*   bptr    = (int*)p;    p += ((size_t)NBUCK + 1) * 4;
    int*   row_ptr = (int*)p;    p += ((size_t)N_NODES + 1) * 4;
    int*   tot     = (int*)p;    p += (size_t)NBUCK * 4;

    // gcount/goff alias hA+hB region: dead before spmm<0> writes hA
    int* gcount = (int*)hA;                       // 512*782*4 = 1.6 MB
    int* goff   = gcount + (size_t)NPART * NBUCK; // 1.6 MB

    const int n4 = (int)(feat / 4);
    cvt_fp16       <<<(n4 + 255) / 256, 256, 0, stream>>>(X, Xh);
    count_chunks   <<<NPART, 256, 0, stream>>>(dst, gcount);
    scan_chunks    <<<NBUCK, NPART, 0, stream>>>(gcount, goff, tot);
    scan_tot       <<<1, 1024, 0, stream>>>(tot, bptr, row_ptr);
    partition_chunks<<<NPART, 256, 0, stream>>>(src, dst, ew, goff, bptr, bedges);
    sort_bucket    <<<NBUCK, 256, 0, stream>>>(bedges, bptr, sedges, row_ptr);

    const int nblk = (N_NODES + 3) / 4;   // 4 waves/block
    spmm_pull<0><<<nblk, 256, 0, stream>>>(Xh, row_ptr, sedges, hA, out, X, hA, hB);
    spmm_pull<1><<<nblk, 256, 0, stream>>>(hA, row_ptr, sedges, hB, out, X, hA, hB);
    spmm_pull<2><<<nblk, 256, 0, stream>>>(hB, row_ptr, sedges, (__half*)nullptr, out, X, hA, hB);
}

// Round 8
// 290.479 us; speedup vs baseline: 1.1738x; 1.1738x over previous
//
#include <hip/hip_runtime.h>
#include <hip/hip_fp16.h>

#define N_NODES 100000
#define D_FEAT  64
#define N_EDGES 1600000
#define NPB     128                         // nodes per bucket (dst >> 7)
#define NBUCK   ((N_NODES + NPB - 1) / NPB) // 782
#define NPART   512                         // partition chunks
#define CHUNK   (N_EDGES / NPART)           // 3125 (exact)
#define PULL_BLOCKS 2048                    // 8 blocks/CU, persistent

// ---------- phase 0: X -> fp16 copy ----------
__global__ void cvt_fp16(const float* __restrict__ X, __half* __restrict__ Xh) {
    int i = blockIdx.x * blockDim.x + threadIdx.x;
    const int n4 = N_NODES * D_FEAT / 4;
    if (i >= n4) return;
    float4 v = ((const float4*)X)[i];
    __half2 a = __floats2half2_rn(v.x, v.y);
    __half2 b = __floats2half2_rn(v.z, v.w);
    ((__half2*)Xh)[2 * i]     = a;
    ((__half2*)Xh)[2 * i + 1] = b;
}

// ---------- phase 1: per-chunk histogram over buckets ----------
__global__ void count_chunks(const int* __restrict__ dst, int* __restrict__ gcount) {
    __shared__ int h[NBUCK];
    for (int i = threadIdx.x; i < NBUCK; i += blockDim.x) h[i] = 0;
    __syncthreads();
    const int beg = blockIdx.x * CHUNK, end = beg + CHUNK;
    for (int i = beg + threadIdx.x; i < end; i += blockDim.x)
        atomicAdd(&h[dst[i] >> 7], 1);
    __syncthreads();
    for (int i = threadIdx.x; i < NBUCK; i += blockDim.x)
        gcount[blockIdx.x * NBUCK + i] = h[i];
}

// ---------- phase 2a: per-bucket scan over the 512 chunks ----------
__global__ __launch_bounds__(NPART) void scan_chunks(const int* __restrict__ gcount,
                                                     int* __restrict__ goff,
                                                     int* __restrict__ tot) {
    __shared__ int tmp[NPART];
    const int t = threadIdx.x;      // chunk id
    const int b = blockIdx.x;       // bucket id
    int v = gcount[t * NBUCK + b];
    tmp[t] = v;
    __syncthreads();
    for (int off = 1; off < NPART; off <<= 1) {
        int u = (t >= off) ? tmp[t - off] : 0;
        __syncthreads();
        tmp[t] += u;
        __syncthreads();
    }
    goff[t * NBUCK + b] = tmp[t] - v;
    if (t == NPART - 1) tot[b] = tmp[t];
}

// ---------- phase 2b: scan 782 bucket totals -> bptr ----------
__global__ void scan_tot(const int* __restrict__ tot, int* __restrict__ bptr,
                         int* __restrict__ row_ptr) {
    __shared__ int tmp[1024];
    const int t = threadIdx.x;
    int v = (t < NBUCK) ? tot[t] : 0;
    tmp[t] = v;
    __syncthreads();
    for (int off = 1; off < 1024; off <<= 1) {
        int u = (t >= off) ? tmp[t - off] : 0;
        __syncthreads();
        tmp[t] += u;
        __syncthreads();
    }
    if (t < NBUCK) bptr[t] = tmp[t] - v;
    if (t == 0) {
        bptr[NBUCK] = N_EDGES;
        row_ptr[N_NODES] = N_EDGES;
    }
}

// ---------- phase 3: deterministic partition via LDS cursors ----------
// packed word = src | (dst & 127) << 17   (src < 2^17)
__global__ void partition_chunks(const int* __restrict__ src, const int* __restrict__ dst,
                                 const float* __restrict__ ew, const int* __restrict__ goff,
                                 const int* __restrict__ bptr, int2* __restrict__ bedges) {
    __shared__ int cur[NBUCK];
    for (int i = threadIdx.x; i < NBUCK; i += blockDim.x)
        cur[i] = goff[blockIdx.x * NBUCK + i] + bptr[i];
    __syncthreads();
    const int beg = blockIdx.x * CHUNK, end = beg + CHUNK;
    for (int i = beg + threadIdx.x; i < end; i += blockDim.x) {
        int d = dst[i];
        int b = d >> 7;
        int p = atomicAdd(&cur[b], 1);
        int2 e;
        e.x = src[i] | ((d & (NPB - 1)) << 17);
        e.y = __float_as_int(ew[i]);
        bedges[p] = e;
    }
}

// ---------- phase 4: per-bucket LDS counting sort -> dst-sorted edges + row_ptr ----------
__global__ void sort_bucket(const int2* __restrict__ bedges, const int* __restrict__ bptr,
                            int2* __restrict__ sedges, int* __restrict__ row_ptr) {
    __shared__ int cnt[NPB];
    __shared__ int sc[NPB];
    __shared__ int cur[NPB];
    const int b = blockIdx.x;
    const int t = threadIdx.x;
    const int beg = bptr[b];
    const int end = bptr[b + 1];

    if (t < NPB) cnt[t] = 0;
    __syncthreads();
    for (int i = beg + t; i < end; i += blockDim.x)
        atomicAdd(&cnt[bedges[i].x >> 17], 1);
    __syncthreads();

    if (t < NPB) sc[t] = cnt[t];
    __syncthreads();
    for (int off = 1; off < NPB; off <<= 1) {
        int v = (t >= off && t < NPB) ? sc[t - off] : 0;
        __syncthreads();
        if (t < NPB) sc[t] += v;
        __syncthreads();
    }
    if (t < NPB) {
        int ex = sc[t] - cnt[t];
        cur[t] = ex;
        int node = b * NPB + t;
        if (node < N_NODES) row_ptr[node] = beg + ex;
    }
    __syncthreads();

    for (int i = beg + t; i < end; i += blockDim.x) {
        int2 e = bedges[i];
        int dl = e.x >> 17;
        int p = atomicAdd(&cur[dl], 1);
        int2 o;
        o.x = e.x & 0x1FFFF;
        o.y = e.y;
        sedges[beg + p] = o;
    }
}

// ---------- phase 5: pull SpMM — persistent waves, half2 gathers (2 edges/load) ----------
// Half-wave 0 (lanes 0-31) handles even edges, half-wave 1 odd edges.
// Lane's half2 = features (2*sub, 2*sub+1). Cross-half reduce via shfl_xor(32).
// MODE 0/1: hout = half2(a) | MODE 2: out = (X + h1 + h2 + a) * 0.25
template <int MODE>
__global__ __launch_bounds__(256) void spmm_pull(const __half* __restrict__ hprev,
                                                 const int* __restrict__ row_ptr,
                                                 const int2* __restrict__ edges,
                                                 __half* __restrict__ hout,
                                                 float* __restrict__ out,
                                                 const float* __restrict__ X,
                                                 const __half* __restrict__ h1,
                                                 const __half* __restrict__ h2) {
    const int wave   = blockIdx.x * 4 + (threadIdx.x >> 6);
    const int lane   = threadIdx.x & 63;
    const int half   = lane >> 5;          // 0 = even edges, 1 = odd edges
    const int sub    = lane & 31;          // half2 feature-pair index
    const int nwaves = gridDim.x * 4;

    for (int node = wave; node < N_NODES; node += nwaves) {
        int beg = __builtin_amdgcn_readfirstlane(row_ptr[node]);
        int end = __builtin_amdgcn_readfirstlane(row_ptr[node + 1]);

        float ax = 0.0f, ay = 0.0f;
        int j = beg;
        // full batches: no clamps -> consecutive scalar edge loads merge wide
        for (; j + 16 <= end; j += 16) {
            unsigned int t[8]; float w[8];
            #pragma unroll
            for (int k = 0; k < 8; ++k) {
                int2 e0 = edges[j + 2 * k];
                int2 e1 = edges[j + 2 * k + 1];
                int   s = half ? e1.x : e0.x;
                w[k]    = __int_as_float(half ? e1.y : e0.y);
                t[k] = *(const unsigned int*)(hprev + (((size_t)s << 6) | (2 * sub)));
            }
            #pragma unroll
            for (int k = 0; k < 8; ++k) {
                float2 f = __half22float2(*(__half2*)&t[k]);
                ax += f.x * w[k];
                ay += f.y * w[k];
            }
        }
        // tail batch: clamped indices, zeroed weights
        if (j < end) {
            unsigned int t[8]; float w[8];
            #pragma unroll
            for (int k = 0; k < 8; ++k) {
                int i0 = j + 2 * k, i1 = i0 + 1;
                int2 e0 = edges[(i0 < end) ? i0 : beg];
                int2 e1 = edges[(i1 < end) ? i1 : beg];
                int   s = half ? e1.x : e0.x;
                float w0 = (i0 < end) ? __int_as_float(e0.y) : 0.0f;
                float w1 = (i1 < end) ? __int_as_float(e1.y) : 0.0f;
                w[k] = half ? w1 : w0;
                t[k] = *(const unsigned int*)(hprev + (((size_t)s << 6) | (2 * sub)));
            }
            #pragma unroll
            for (int k = 0; k < 8; ++k) {
                float2 f = __half22float2(*(__half2*)&t[k]);
                ax += f.x * w[k];
                ay += f.y * w[k];
            }
        }

        ax += __shfl_xor(ax, 32);
        ay += __shfl_xor(ay, 32);

        if (half == 0) {
            size_t base = (size_t)node * 32 + sub;   // half2/float2 granularity
            if (MODE == 2) {
                float2 x  = ((const float2*)X)[base];
                float2 f1 = __half22float2(((const __half2*)h1)[base]);
                float2 f2 = __half22float2(((const __half2*)h2)[base]);
                float2 r;
                r.x = (x.x + f1.x + f2.x + ax) * 0.25f;
                r.y = (x.y + f1.y + f2.y + ay) * 0.25f;
                ((float2*)out)[base] = r;
            } else {
                ((__half2*)hout)[base] = __floats2half2_rn(ax, ay);
            }
        }
    }
}

extern "C" void kernel_launch(void* const* d_in, const int* in_sizes, int n_in,
                              void* d_out, int out_size, void* d_ws, size_t ws_size,
                              hipStream_t stream) {
    const float* X   = (const float*)d_in[0];
    const int*   src = (const int*)  d_in[1];
    const int*   dst = (const int*)  d_in[2];
    const float* ew  = (const float*)d_in[3];
    float* out = (float*)d_out;

    const size_t feat = (size_t)N_NODES * D_FEAT;

    char* p = (char*)d_ws;
    __half* hA     = (__half*)p; p += feat * sizeof(__half);       // 12.8 MB
    __half* hB     = (__half*)p; p += feat * sizeof(__half);       // 12.8 MB
    __half* Xh     = (__half*)p; p += feat * sizeof(__half);       // 12.8 MB
    int2*  bedges  = (int2*)p;   p += (size_t)N_EDGES * 8;         // 12.8 MB
    int2*  sedges  = (int2*)p;   p += (size_t)N_EDGES * 8;         // 12.8 MB
    int*   bptr    = (int*)p;    p += ((size_t)NBUCK + 1) * 4;
    int*   row_ptr = (int*)p;    p += ((size_t)N_NODES + 1) * 4;
    int*   tot     = (int*)p;    p += (size_t)NBUCK * 4;

    // gcount/goff alias hA+hB region: dead before spmm<0> writes hA
    int* gcount = (int*)hA;                       // 512*782*4 = 1.6 MB
    int* goff   = gcount + (size_t)NPART * NBUCK; // 1.6 MB

    const int n4 = (int)(feat / 4);
    cvt_fp16       <<<(n4 + 255) / 256, 256, 0, stream>>>(X, Xh);
    count_chunks   <<<NPART, 256, 0, stream>>>(dst, gcount);
    scan_chunks    <<<NBUCK, NPART, 0, stream>>>(gcount, goff, tot);
    scan_tot       <<<1, 1024, 0, stream>>>(tot, bptr, row_ptr);
    partition_chunks<<<NPART, 256, 0, stream>>>(src, dst, ew, goff, bptr, bedges);
    sort_bucket    <<<NBUCK, 256, 0, stream>>>(bedges, bptr, sedges, row_ptr);

    spmm_pull<0><<<PULL_BLOCKS, 256, 0, stream>>>(Xh, row_ptr, sedges, hA, out, X, hA, hB);
    spmm_pull<1><<<PULL_BLOCKS, 256, 0, stream>>>(hA, row_ptr, sedges, hB, out, X, hA, hB);
    spmm_pull<2><<<PULL_BLOCKS, 256, 0, stream>>>(hB, row_ptr, sedges, (__half*)nullptr, out, X, hA, hB);
}

// Round 9
// 252.835 us; speedup vs baseline: 1.3486x; 1.1489x over previous
//
#include <hip/hip_runtime.h>
#include <hip/hip_fp16.h>

#define N_NODES 100000
#define D_FEAT  64
#define N_EDGES 1600000
#define NPB     128                         // nodes per bucket (dst >> 7)
#define NBUCK   ((N_NODES + NPB - 1) / NPB) // 782
#define NPART   512                         // partition chunks
#define CHUNK   (N_EDGES / NPART)           // 3125 (exact)
#define PULL_BLOCKS 2048                    // 8 blocks/CU, persistent
#define GRP     4                           // nodes per pull group (1 per wave)
#define GCAP    512                         // max edges staged per group
#define GPAD    (GCAP + 64)                 // staged slots incl. per-node padding
#define SORT_CAP 3072                       // LDS-staged sort capacity (bucket mean 2046)

// ---------- phase 0+1 fused: X -> fp16 AND per-chunk bucket histogram ----------
__global__ __launch_bounds__(256) void cvt_count(const float* __restrict__ X,
                                                 __half* __restrict__ Xh,
                                                 const int* __restrict__ dst,
                                                 int* __restrict__ gcount) {
    __shared__ int h[NBUCK];
    for (int i = threadIdx.x; i < NBUCK; i += 256) h[i] = 0;
    const int n4 = N_NODES * D_FEAT / 4;
    for (int i = blockIdx.x * 256 + threadIdx.x; i < n4; i += NPART * 256) {
        float4 v = ((const float4*)X)[i];
        ((__half2*)Xh)[2 * i]     = __floats2half2_rn(v.x, v.y);
        ((__half2*)Xh)[2 * i + 1] = __floats2half2_rn(v.z, v.w);
    }
    __syncthreads();
    const int beg = blockIdx.x * CHUNK, end = beg + CHUNK;
    for (int i = beg + threadIdx.x; i < end; i += 256)
        atomicAdd(&h[dst[i] >> 7], 1);
    __syncthreads();
    for (int i = threadIdx.x; i < NBUCK; i += 256)
        gcount[blockIdx.x * NBUCK + i] = h[i];
}

// ---------- phase 2a: per-bucket scan over the 512 chunks ----------
__global__ __launch_bounds__(NPART) void scan_chunks(const int* __restrict__ gcount,
                                                     int* __restrict__ goff,
                                                     int* __restrict__ tot) {
    __shared__ int tmp[NPART];
    const int t = threadIdx.x;      // chunk id
    const int b = blockIdx.x;       // bucket id
    int v = gcount[t * NBUCK + b];
    tmp[t] = v;
    __syncthreads();
    for (int off = 1; off < NPART; off <<= 1) {
        int u = (t >= off) ? tmp[t - off] : 0;
        __syncthreads();
        tmp[t] += u;
        __syncthreads();
    }
    goff[t * NBUCK + b] = tmp[t] - v;
    if (t == NPART - 1) tot[b] = tmp[t];
}

// ---------- phase 2b: scan 782 bucket totals -> bptr ----------
__global__ void scan_tot(const int* __restrict__ tot, int* __restrict__ bptr,
                         int* __restrict__ row_ptr) {
    __shared__ int tmp[1024];
    const int t = threadIdx.x;
    int v = (t < NBUCK) ? tot[t] : 0;
    tmp[t] = v;
    __syncthreads();
    for (int off = 1; off < 1024; off <<= 1) {
        int u = (t >= off) ? tmp[t - off] : 0;
        __syncthreads();
        tmp[t] += u;
        __syncthreads();
    }
    if (t < NBUCK) bptr[t] = tmp[t] - v;
    if (t == 0) {
        bptr[NBUCK] = N_EDGES;
        row_ptr[N_NODES] = N_EDGES;
    }
}

// ---------- phase 3: deterministic partition via LDS cursors ----------
// packed word = src | (dst & 127) << 17   (src < 2^17)
__global__ void partition_chunks(const int* __restrict__ src, const int* __restrict__ dst,
                                 const float* __restrict__ ew, const int* __restrict__ goff,
                                 const int* __restrict__ bptr, int2* __restrict__ bedges) {
    __shared__ int cur[NBUCK];
    for (int i = threadIdx.x; i < NBUCK; i += blockDim.x)
        cur[i] = goff[blockIdx.x * NBUCK + i] + bptr[i];
    __syncthreads();
    const int beg = blockIdx.x * CHUNK, end = beg + CHUNK;
    for (int i = beg + threadIdx.x; i < end; i += blockDim.x) {
        int d = dst[i];
        int b = d >> 7;
        int p = atomicAdd(&cur[b], 1);
        int2 e;
        e.x = src[i] | ((d & (NPB - 1)) << 17);
        e.y = __float_as_int(ew[i]);
        bedges[p] = e;
    }
}

// ---------- phase 4: per-bucket counting sort (LDS-staged) ----------
__global__ __launch_bounds__(256) void sort_bucket(const int2* __restrict__ bedges,
                                                   const int* __restrict__ bptr,
                                                   int2* __restrict__ sedges,
                                                   int* __restrict__ row_ptr) {
    __shared__ int cnt[NPB], sc[NPB], cur[NPB];
    __shared__ int2 buf[SORT_CAP];
    const int b = blockIdx.x, t = threadIdx.x;
    const int beg = bptr[b], end = bptr[b + 1];
    const int n = end - beg;
    const bool staged = (n <= SORT_CAP);

    if (t < NPB) cnt[t] = 0;
    __syncthreads();
    if (staged) {
        for (int i = t; i < n; i += 256) {
            int2 e = bedges[beg + i];
            buf[i] = e;
            atomicAdd(&cnt[e.x >> 17], 1);
        }
    } else {
        for (int i = t; i < n; i += 256)
            atomicAdd(&cnt[bedges[beg + i].x >> 17], 1);
    }
    __syncthreads();

    if (t < NPB) sc[t] = cnt[t];
    __syncthreads();
    for (int off = 1; off < NPB; off <<= 1) {
        int v = (t >= off && t < NPB) ? sc[t - off] : 0;
        __syncthreads();
        if (t < NPB) sc[t] += v;
        __syncthreads();
    }
    if (t < NPB) {
        cur[t] = sc[t] - cnt[t];
        int node = b * NPB + t;
        if (node < N_NODES) row_ptr[node] = beg + sc[t] - cnt[t];
    }
    __syncthreads();

    if (staged) {
        for (int i = t; i < n; i += 256) {
            int2 e = buf[i];
            int p = atomicAdd(&cur[e.x >> 17], 1);
            sedges[beg + p] = make_int2(e.x & 0x1FFFF, e.y);
        }
    } else {
        for (int i = t; i < n; i += 256) {
            int2 e = bedges[beg + i];
            int p = atomicAdd(&cur[e.x >> 17], 1);
            sedges[beg + p] = make_int2(e.x & 0x1FFFF, e.y);
        }
    }
}

// ---------- phase 5: pull SpMM — LDS-staged edges, zero-select inner loop ----------
// Block = 4 waves = 4 consecutive nodes; group's edges staged once into LDS with
// per-node padding to 16 (dummy edges: src=0, w=0). Half-wave 0 eats even edges,
// half-wave 1 odd, via per-lane ds_read_b64 (2-addr broadcast, conflict-free).
// MODE 0/1: hout = half2(a) | MODE 2: out = (X + h1 + h2 + a) * 0.25
template <int MODE>
__global__ __launch_bounds__(256) void spmm_pull(const __half* __restrict__ hprev,
                                                 const int* __restrict__ row_ptr,
                                                 const int2* __restrict__ edges,
                                                 __half* __restrict__ hout,
                                                 float* __restrict__ out,
                                                 const float* __restrict__ X,
                                                 const __half* __restrict__ h1,
                                                 const __half* __restrict__ h2) {
    __shared__ int2 ebuf[GPAD];
    __shared__ int  rp[GRP + 1];
    __shared__ int  pbase[GRP + 1];
    const int t    = threadIdx.x;
    const int wid  = t >> 6;
    const int lane = t & 63;
    const int half = lane >> 5;
    const int sub  = lane & 31;
    const int ngroups = (N_NODES + GRP - 1) / GRP;

    for (int g = blockIdx.x; g < ngroups; g += gridDim.x) {
        const int n0 = g * GRP;
        if (t <= GRP) {
            int nn = n0 + t;
            rp[t] = row_ptr[nn < N_NODES ? nn : N_NODES];
        }
        __syncthreads();
        const int B = rp[0], E = rp[GRP];
        const int cnt = E - B;

        if (cnt <= GCAP) {
            if (t == 0) {
                int o = 0;
                #pragma unroll
                for (int i = 0; i < GRP; ++i) {
                    pbase[i] = o;
                    o += (rp[i + 1] - rp[i] + 15) & ~15;
                }
                pbase[GRP] = o;
            }
            __syncthreads();
            // scatter real edges + zero the pad gaps (disjoint slots, one phase)
            for (int i = t; i < cnt; i += 256) {
                int p = B + i;
                int nd = (p >= rp[1]) + (p >= rp[2]) + (p >= rp[3]);
                ebuf[pbase[nd] + (p - rp[nd])] = edges[p];
            }
            if (t < GRP * 15) {
                int i = t / 15;
                int slot = pbase[i] + (rp[i + 1] - rp[i]) + (t % 15);
                if (slot < pbase[i + 1]) ebuf[slot] = make_int2(0, 0);
            }
            __syncthreads();
            // consume: wave wid -> node n0+wid; all batches full (padded)
            int node = n0 + wid;
            if (node < N_NODES) {
                const int d  = rp[wid + 1] - rp[wid];
                const int pb = pbase[wid] + half;
                const int nb = (d + 15) >> 4;
                float ax = 0.0f, ay = 0.0f;
                for (int bi = 0; bi < nb; ++bi) {
                    const int base = pb + bi * 16;
                    unsigned tv[8]; float w[8];
                    #pragma unroll
                    for (int k = 0; k < 8; ++k) {
                        int2 e = ebuf[base + 2 * k];     // ds_read_b64, imm offset
                        w[k]  = __int_as_float(e.y);
                        tv[k] = *(const unsigned*)(hprev + (((size_t)e.x << 6) | (2 * sub)));
                    }
                    #pragma unroll
                    for (int k = 0; k < 8; ++k) {
                        float2 f = __half22float2(*(__half2*)&tv[k]);
                        ax += f.x * w[k];
                        ay += f.y * w[k];
                    }
                }
                ax += __shfl_xor(ax, 32);
                ay += __shfl_xor(ay, 32);
                if (half == 0) {
                    size_t bo = (size_t)node * 32 + sub;
                    if (MODE == 2) {
                        float2 x  = ((const float2*)X)[bo];
                        float2 f1 = __half22float2(((const __half2*)h1)[bo]);
                        float2 f2 = __half22float2(((const __half2*)h2)[bo]);
                        ((float2*)out)[bo] = make_float2((x.x + f1.x + f2.x + ax) * 0.25f,
                                                         (x.y + f1.y + f2.y + ay) * 0.25f);
                    } else {
                        ((__half2*)hout)[bo] = __floats2half2_rn(ax, ay);
                    }
                }
            }
            __syncthreads();
        } else {
            // fallback (statistically never): r8-style global scalar path
            int node = n0 + wid;
            if (node < N_NODES) {
                int beg = __builtin_amdgcn_readfirstlane(row_ptr[node]);
                int end = __builtin_amdgcn_readfirstlane(row_ptr[node + 1]);
                float ax = 0.0f, ay = 0.0f;
                for (int j = beg; j < end; j += 16) {
                    unsigned tv[8]; float w[8];
                    #pragma unroll
                    for (int k = 0; k < 8; ++k) {
                        int i0 = j + 2 * k, i1 = i0 + 1;
                        int2 e0 = edges[(i0 < end) ? i0 : beg];
                        int2 e1 = edges[(i1 < end) ? i1 : beg];
                        int s = half ? e1.x : e0.x;
                        float w0 = (i0 < end) ? __int_as_float(e0.y) : 0.0f;
                        float w1 = (i1 < end) ? __int_as_float(e1.y) : 0.0f;
                        w[k] = half ? w1 : w0;
                        tv[k] = *(const unsigned*)(hprev + (((size_t)s << 6) | (2 * sub)));
                    }
                    #pragma unroll
                    for (int k = 0; k < 8; ++k) {
                        float2 f = __half22float2(*(__half2*)&tv[k]);
                        ax += f.x * w[k];
                        ay += f.y * w[k];
                    }
                }
                ax += __shfl_xor(ax, 32);
                ay += __shfl_xor(ay, 32);
                if (half == 0) {
                    size_t bo = (size_t)node * 32 + sub;
                    if (MODE == 2) {
                        float2 x  = ((const float2*)X)[bo];
                        float2 f1 = __half22float2(((const __half2*)h1)[bo]);
                        float2 f2 = __half22float2(((const __half2*)h2)[bo]);
                        ((float2*)out)[bo] = make_float2((x.x + f1.x + f2.x + ax) * 0.25f,
                                                         (x.y + f1.y + f2.y + ay) * 0.25f);
                    } else {
                        ((__half2*)hout)[bo] = __floats2half2_rn(ax, ay);
                    }
                }
            }
            __syncthreads();
        }
    }
}

extern "C" void kernel_launch(void* const* d_in, const int* in_sizes, int n_in,
                              void* d_out, int out_size, void* d_ws, size_t ws_size,
                              hipStream_t stream) {
    const float* X   = (const float*)d_in[0];
    const int*   src = (const int*)  d_in[1];
    const int*   dst = (const int*)  d_in[2];
    const float* ew  = (const float*)d_in[3];
    float* out = (float*)d_out;

    const size_t feat = (size_t)N_NODES * D_FEAT;

    char* p = (char*)d_ws;
    __half* hA     = (__half*)p; p += feat * sizeof(__half);       // 12.8 MB
    __half* hB     = (__half*)p; p += feat * sizeof(__half);       // 12.8 MB
    __half* Xh     = (__half*)p; p += feat * sizeof(__half);       // 12.8 MB
    int2*  bedges  = (int2*)p;   p += (size_t)N_EDGES * 8;         // 12.8 MB
    int2*  sedges  = (int2*)p;   p += (size_t)N_EDGES * 8;         // 12.8 MB
    int*   bptr    = (int*)p;    p += ((size_t)NBUCK + 1) * 4;
    int*   row_ptr = (int*)p;    p += ((size_t)N_NODES + 1) * 4;
    int*   tot     = (int*)p;    p += (size_t)NBUCK * 4;

    // gcount/goff alias hA+hB region: dead before spmm<0> writes hA
    int* gcount = (int*)hA;                       // 512*782*4 = 1.6 MB
    int* goff   = gcount + (size_t)NPART * NBUCK; // 1.6 MB

    cvt_count      <<<NPART, 256, 0, stream>>>(X, Xh, dst, gcount);
    scan_chunks    <<<NBUCK, NPART, 0, stream>>>(gcount, goff, tot);
    scan_tot       <<<1, 1024, 0, stream>>>(tot, bptr, row_ptr);
    partition_chunks<<<NPART, 256, 0, stream>>>(src, dst, ew, goff, bptr, bedges);
    sort_bucket    <<<NBUCK, 256, 0, stream>>>(bedges, bptr, sedges, row_ptr);

    spmm_pull<0><<<PULL_BLOCKS, 256, 0, stream>>>(Xh, row_ptr, sedges, hA, out, X, hA, hB);
    spmm_pull<1><<<PULL_BLOCKS, 256, 0, stream>>>(hA, row_ptr, sedges, hB, out, X, hA, hB);
    spmm_pull<2><<<PULL_BLOCKS, 256, 0, stream>>>(hB, row_ptr, sedges, (__half*)nullptr, out, X, hA, hB);
}